// Round 2
// baseline (1698.028 us; speedup 1.0000x reference)
//
#include <hip/hip_runtime.h>

#define N_ROWS 32768
#define DIM    512
#define K_CODES 8192
#define BM 128
#define BN 128
#define BK 32
#define NB (K_CODES / BN)   /* 64 code tiles */
#define MARGIN 3e-3f

typedef short s16x8 __attribute__((ext_vector_type(8)));
typedef float f32x4 __attribute__((ext_vector_type(4)));

__device__ __forceinline__ unsigned short f2bf(float f) {
  unsigned int u = __float_as_uint(f);
  u = (u + 0x7fffu + ((u >> 16) & 1u)) >> 16;   // RNE
  return (unsigned short)u;
}

__device__ __forceinline__ void gload_lds16(const void* g, void* l) {
  __builtin_amdgcn_global_load_lds(
      (const __attribute__((address_space(1))) void*)g,
      (__attribute__((address_space(3))) void*)l,
      16, 0, 0);
}

__device__ __forceinline__ float blockReduceSum256(float v, float* red) {
#pragma unroll
  for (int o = 32; o; o >>= 1) v += __shfl_xor(v, o);
  if ((threadIdx.x & 63) == 0) red[threadIdx.x >> 6] = v;
  __syncthreads();
  float s = red[0] + red[1] + red[2] + red[3];
  __syncthreads();
  return s;
}

__device__ __forceinline__ float blockReduceMax256(float v, float* red) {
#pragma unroll
  for (int o = 32; o; o >>= 1) v = fmaxf(v, __shfl_xor(v, o));
  if ((threadIdx.x & 63) == 0) red[threadIdx.x >> 6] = v;
  __syncthreads();
  float s = fmaxf(fmaxf(red[0], red[1]), fmaxf(red[2], red[3]));
  __syncthreads();
  return s;
}

// ---- normalize codebook rows -> bf16, keep norm and sum(wn^2) ----
__global__ void prep_w(const float* __restrict__ W, unsigned short* __restrict__ wn16,
                       float* __restrict__ wnorm, float* __restrict__ wn2) {
  __shared__ float red[4];
  int k = blockIdx.x, t = threadIdx.x;
  float2 wv = *(const float2*)&W[(size_t)k * DIM + t * 2];
  float tot = blockReduceSum256(wv.x * wv.x + wv.y * wv.y, red);
  float nrm = fmaxf(sqrtf(tot), 1e-12f);
  float q0 = wv.x / nrm, q1 = wv.y / nrm;
  unsigned short b0 = f2bf(q0), b1 = f2bf(q1);
  *(ushort2*)&wn16[(size_t)k * DIM + t * 2] = make_ushort2(b0, b1);
  float s2 = blockReduceSum256(q0 * q0 + q1 * q1, red);
  if (t == 0) { wnorm[k] = nrm; wn2[k] = s2; }
}

// ---- normalize x rows -> bf16, keep norm ----
__global__ void prep_x(const float* __restrict__ X, unsigned short* __restrict__ xn16,
                       float* __restrict__ xnorm) {
  __shared__ float red[4];
  int n = blockIdx.x, t = threadIdx.x;
  float2 xv = *(const float2*)&X[(size_t)n * DIM + t * 2];
  float tot = blockReduceSum256(xv.x * xv.x + xv.y * xv.y, red);
  float nrm = fmaxf(sqrtf(tot), 1e-12f);
  *(ushort2*)&xn16[(size_t)n * DIM + t * 2] =
      make_ushort2(f2bf(xv.x / nrm), f2bf(xv.y / nrm));
  if (t == 0) xnorm[n] = nrm;
}

// ---- bf16 MFMA GEMM (scores = xn.wn^T), per-row top-2 within each 128-code tile ----
__global__ __launch_bounds__(256, 2) void gemm_top2(
    const unsigned short* __restrict__ xn16, const unsigned short* __restrict__ wn16,
    float* __restrict__ pv, int* __restrict__ pi) {
  union SMem {
    struct { unsigned short A[BM * BK]; unsigned short B[BN * BK]; } st;
    float sc[BM * 129];
  };
  __shared__ SMem sm;
  int bx = blockIdx.x;              // code tile 0..63
  int by = blockIdx.y;              // row tile 0..255
  int t = threadIdx.x;
  int w = t >> 6, l = t & 63;
  int wr = w >> 1, wc = w & 1;      // wave quadrant (64x64)
  f32x4 acc[4][4] = {};

  const unsigned short* Ab = xn16 + (size_t)by * BM * DIM;
  const unsigned short* Bb = wn16 + (size_t)bx * BN * DIM;

  for (int k0 = 0; k0 < DIM; k0 += BK) {
#pragma unroll
    for (int i = 0; i < 2; i++) {
      int c = i * 256 + t;          // 16B chunk id, 512 chunks per tile
      int r = c >> 2, s = c & 3;    // row, 16B slot within 64B row
      gload_lds16(Ab + (size_t)r * DIM + k0 + s * 8, &sm.st.A[c * 8]);
      gload_lds16(Bb + (size_t)r * DIM + k0 + s * 8, &sm.st.B[c * 8]);
    }
    __syncthreads();                // drains vmcnt before LDS reads
    s16x8 aF[4], bF[4];
    int koff = (l >> 4) * 8;
    int rr = l & 15;
#pragma unroll
    for (int m = 0; m < 4; m++)
      aF[m] = *(const s16x8*)&sm.st.A[(wr * 64 + m * 16 + rr) * BK + koff];
#pragma unroll
    for (int n = 0; n < 4; n++)
      bF[n] = *(const s16x8*)&sm.st.B[(wc * 64 + n * 16 + rr) * BK + koff];
#pragma unroll
    for (int m = 0; m < 4; m++)
#pragma unroll
      for (int n = 0; n < 4; n++)
        acc[m][n] = __builtin_amdgcn_mfma_f32_16x16x32_bf16(aF[m], bF[n], acc[m][n], 0, 0, 0);
    __syncthreads();
  }

  // scores -> LDS (C/D layout: row=(l>>4)*4+r, col=l&15) [m89-verified mapping]
#pragma unroll
  for (int m = 0; m < 4; m++)
#pragma unroll
    for (int n = 0; n < 4; n++)
#pragma unroll
      for (int r = 0; r < 4; r++) {
        int rl = wr * 64 + m * 16 + (l >> 4) * 4 + r;
        int cl = wc * 64 + n * 16 + (l & 15);
        sm.sc[rl * 129 + cl] = acc[m][n][r];
      }
  __syncthreads();

  // parallel top-2: thread t scans 64-col half of row t>>1, then shfl-merge pairs
  {
    int r = t >> 1, h = t & 1;
    float b1 = -1e30f, b2 = -1e30f; int i1 = 0, i2 = 0;
    const float* rowp = &sm.sc[r * 129 + h * 64];
#pragma unroll 8
    for (int j = 0; j < 64; j++) {
      float v = rowp[j];
      int c2 = h * 64 + j;
      if (v > b1) { b2 = b1; i2 = i1; b1 = v; i1 = c2; }
      else if (v > b2) { b2 = v; i2 = c2; }
    }
    // merge with partner (t^1, same wave)
    float ob1 = __shfl_xor(b1, 1), ob2 = __shfl_xor(b2, 1);
    int oi1 = __shfl_xor(i1, 1), oi2 = __shfl_xor(i2, 1);
    // top-2 of {b1,b2,ob1,ob2}
    float m1, m2; int j1, j2;
    if (b1 >= ob1) { m1 = b1; j1 = i1; m2 = fmaxf(b2, ob1); j2 = (b2 >= ob1) ? i2 : oi1; }
    else           { m1 = ob1; j1 = oi1; m2 = fmaxf(ob2, b1); j2 = (ob2 >= b1) ? oi2 : i1; }
    if (h == 0) {
      size_t rowg = (size_t)by * BM + r;
      pv[rowg * (NB * 2) + bx * 2 + 0] = m1;
      pv[rowg * (NB * 2) + bx * 2 + 1] = m2;
      pi[rowg * (NB * 2) + bx * 2 + 0] = bx * BN + j1;
      pi[rowg * (NB * 2) + bx * 2 + 1] = bx * BN + j2;
    }
  }
}

// ---- per row: pick candidates, rescore in fp32, emit quantized_st + loss + index ----
__global__ void reduce_rescore(
    const float* __restrict__ X, const float* __restrict__ W,
    const float* __restrict__ xnorm, const float* __restrict__ wnorm,
    const float* __restrict__ wn2, const float* __restrict__ pv,
    const int* __restrict__ pi, float* __restrict__ out,
    double* __restrict__ accum, float* __restrict__ outIdx) {
  __shared__ float red[4];
  __shared__ float xnL[DIM];
  __shared__ int candList[NB * 2];
  __shared__ int candCnt;
  int row = blockIdx.x, t = threadIdx.x;

  float v = -1e30f;
  if (t < NB * 2) v = pv[(size_t)row * (NB * 2) + t];
  if (t == 0) candCnt = 0;
  float gmax = blockReduceMax256(v, red);   // trailing sync makes candCnt=0 visible
  if (t < NB * 2 && v >= gmax - MARGIN) {
    int p = atomicAdd(&candCnt, 1);
    candList[p] = pi[(size_t)row * (NB * 2) + t];
  }
  float xnrm = xnorm[row];
  for (int d = t; d < DIM; d += 256) xnL[d] = X[(size_t)row * DIM + d] / xnrm;
  __syncthreads();

  int cnt = candCnt;
  float bestDist = 1e30f; int bestIdx = 0x7fffffff;
  for (int ci = 0; ci < cnt; ci++) {
    int c = candList[ci];
    float wnr = wnorm[c];
    float part = 0.f;
    for (int d = t; d < DIM; d += 256)
      part += xnL[d] * (W[(size_t)c * DIM + d] / wnr);
    float dot = blockReduceSum256(part, red);
    float dist = wn2[c] - 2.0f * dot;
    if (dist < bestDist || (dist == bestDist && c < bestIdx)) { bestDist = dist; bestIdx = c; }
  }

  int c = bestIdx;
  float wnr = wnorm[c];
  float part = 0.f;
  for (int d = t; d < DIM; d += 256) {
    float q = W[(size_t)c * DIM + d] / wnr;
    float xv = xnL[d];
    out[(size_t)row * DIM + d] = xv + (q - xv);   // straight-through, matches ref fp ops
    float df = q - xv;
    part += df * df;
  }
  float ssum = blockReduceSum256(part, red);
  if (t == 0) {
    atomicAdd(accum, (double)ssum);
    outIdx[row] = (float)c;
  }
}

__global__ void final_loss(const double* __restrict__ accum, float* __restrict__ out) {
  out[0] = (float)(1.25 * accum[0] / (double)((size_t)N_ROWS * DIM));
}

extern "C" void kernel_launch(void* const* d_in, const int* in_sizes, int n_in,
                              void* d_out, int out_size, void* d_ws, size_t ws_size,
                              hipStream_t stream) {
  const float* x = (const float*)d_in[0];
  const float* W = (const float*)d_in[1];
  float* out = (float*)d_out;
  char* ws = (char*)d_ws;

  unsigned short* wn16 = (unsigned short*)(ws);                 //  8 MB
  unsigned short* xn16 = (unsigned short*)(ws + 8388608);       // 32 MB
  float* wnorm = (float*)(ws + 41943040);                       // 32 KB
  float* wn2   = (float*)(ws + 41975808);                       // 32 KB
  float* xnorm = (float*)(ws + 42008576);                       // 128 KB
  float* pv    = (float*)(ws + 42139648);                       // 16 MB
  int*   pi    = (int*)  (ws + 58916864);                       // 16 MB
  double* accum = (double*)(ws + 75694080);                     // 8 B

  hipMemsetAsync(accum, 0, sizeof(double), stream);
  prep_w<<<K_CODES, 256, 0, stream>>>(W, wn16, wnorm, wn2);
  prep_x<<<N_ROWS, 256, 0, stream>>>(x, xn16, xnorm);
  dim3 grid(NB, N_ROWS / BM);
  gemm_top2<<<grid, 256, 0, stream>>>(xn16, wn16, pv, pi);
  reduce_rescore<<<N_ROWS, 256, 0, stream>>>(
      x, W, xnorm, wnorm, wn2, pv, pi, out, accum,
      out + (size_t)N_ROWS * DIM + 1);
  final_loss<<<1, 1, 0, stream>>>(accum, out + (size_t)N_ROWS * DIM);
}

// Round 3
// 1250.201 us; speedup vs baseline: 1.3582x; 1.3582x over previous
//
#include <hip/hip_runtime.h>

#define N_ROWS 32768
#define DIM    512
#define K_CODES 8192
#define BM 128
#define BN 128
#define BK 64
#define NB (K_CODES / BN)   /* 64 code tiles */
#define MARGIN 3e-3f

typedef short s16x8 __attribute__((ext_vector_type(8)));
typedef float f32x4 __attribute__((ext_vector_type(4)));

__device__ __forceinline__ unsigned short f2bf(float f) {
  unsigned int u = __float_as_uint(f);
  u = (u + 0x7fffu + ((u >> 16) & 1u)) >> 16;   // RNE
  return (unsigned short)u;
}

__device__ __forceinline__ void gload_lds16(const void* g, void* l) {
  __builtin_amdgcn_global_load_lds(
      (const __attribute__((address_space(1))) void*)g,
      (__attribute__((address_space(3))) void*)l,
      16, 0, 0);
}

__device__ __forceinline__ float blockReduceSum256(float v, float* red) {
#pragma unroll
  for (int o = 32; o; o >>= 1) v += __shfl_xor(v, o);
  if ((threadIdx.x & 63) == 0) red[threadIdx.x >> 6] = v;
  __syncthreads();
  float s = red[0] + red[1] + red[2] + red[3];
  __syncthreads();
  return s;
}

__device__ __forceinline__ float blockReduceMax256(float v, float* red) {
#pragma unroll
  for (int o = 32; o; o >>= 1) v = fmaxf(v, __shfl_xor(v, o));
  if ((threadIdx.x & 63) == 0) red[threadIdx.x >> 6] = v;
  __syncthreads();
  float s = fmaxf(fmaxf(red[0], red[1]), fmaxf(red[2], red[3]));
  __syncthreads();
  return s;
}

// ---- wave-per-row normalize: 4 rows/block, float4x2 per lane, no syncthreads ----
__global__ void prep_rows(const float* __restrict__ src, unsigned short* __restrict__ dst16,
                          float* __restrict__ norms, float* __restrict__ sq) {
  int row = blockIdx.x * 4 + (threadIdx.x >> 6);
  int l = threadIdx.x & 63;
  const float4* p = (const float4*)&src[(size_t)row * DIM + l * 8];
  float4 v0 = p[0], v1 = p[1];
  float ss = v0.x * v0.x + v0.y * v0.y + v0.z * v0.z + v0.w * v0.w
           + v1.x * v1.x + v1.y * v1.y + v1.z * v1.z + v1.w * v1.w;
#pragma unroll
  for (int o = 32; o; o >>= 1) ss += __shfl_xor(ss, o);
  float nrm = fmaxf(sqrtf(ss), 1e-12f);
  // per-element DIVISION to match F.normalize fp semantics on the rescore path
  float q[8];
  q[0] = v0.x / nrm; q[1] = v0.y / nrm; q[2] = v0.z / nrm; q[3] = v0.w / nrm;
  q[4] = v1.x / nrm; q[5] = v1.y / nrm; q[6] = v1.z / nrm; q[7] = v1.w / nrm;
  s16x8 b;
#pragma unroll
  for (int j = 0; j < 8; j++) b[j] = (short)f2bf(q[j]);
  *(s16x8*)&dst16[(size_t)row * DIM + l * 8] = b;
  if (sq) {
    float s2 = q[0]*q[0] + q[1]*q[1] + q[2]*q[2] + q[3]*q[3]
             + q[4]*q[4] + q[5]*q[5] + q[6]*q[6] + q[7]*q[7];
#pragma unroll
    for (int o = 32; o; o >>= 1) s2 += __shfl_xor(s2, o);
    if (l == 0) sq[row] = s2;
  }
  if (l == 0) norms[row] = nrm;
}

// ---- bf16 MFMA GEMM (scores = xn.wn^T), XOR-swizzled LDS (T2, both-sides) ----
__global__ __launch_bounds__(256, 2) void gemm_top2(
    const unsigned short* __restrict__ xn16, const unsigned short* __restrict__ wn16,
    float* __restrict__ pv, int* __restrict__ pi) {
  union SMem {
    struct { unsigned short A[BM * BK]; unsigned short B[BN * BK]; } st;  // 16KB+16KB
    float sc[BM * 129];                                                   // 66048B
  };
  __shared__ SMem sm;
  int bx = blockIdx.x;              // code tile 0..63
  int by = blockIdx.y;              // row tile 0..255
  int t = threadIdx.x;
  int w = t >> 6, l = t & 63;
  int wr = w >> 1, wc = w & 1;      // wave quadrant (64x64)
  int rr = l & 15, hi = l >> 4;
  f32x4 acc[4][4] = {};

  const unsigned short* Ab = xn16 + (size_t)by * BM * DIM;
  const unsigned short* Bb = wn16 + (size_t)bx * BN * DIM;

  for (int k0 = 0; k0 < DIM; k0 += BK) {
    // stage 128x64 tiles; LDS linear dest, XOR-swizzled global source (rule #21)
#pragma unroll
    for (int i = 0; i < 4; i++) {
      int c = i * 256 + t;          // chunk 0..1023 (16B each)
      int r = c >> 3, sl = c & 7;
      int sg = sl ^ (r & 7);        // source slot: same involution as the read
      gload_lds16(Ab + (size_t)r * DIM + k0 + sg * 8, &sm.st.A[c * 8]);
      gload_lds16(Bb + (size_t)r * DIM + k0 + sg * 8, &sm.st.B[c * 8]);
    }
    __syncthreads();                // compiler drains vmcnt before s_barrier

#pragma unroll
    for (int ks = 0; ks < 2; ks++) {
      s16x8 aF[4], bF[4];
      int s = ks * 4 + hi;          // 16B slot within 128B row
#pragma unroll
      for (int m = 0; m < 4; m++) {
        int row = wr * 64 + m * 16 + rr;
        aF[m] = *(const s16x8*)&sm.st.A[row * BK + ((s ^ (row & 7)) * 8)];
      }
#pragma unroll
      for (int n = 0; n < 4; n++) {
        int row = wc * 64 + n * 16 + rr;
        bF[n] = *(const s16x8*)&sm.st.B[row * BK + ((s ^ (row & 7)) * 8)];
      }
#pragma unroll
      for (int m = 0; m < 4; m++)
#pragma unroll
        for (int n = 0; n < 4; n++)
          acc[m][n] = __builtin_amdgcn_mfma_f32_16x16x32_bf16(aF[m], bF[n], acc[m][n], 0, 0, 0);
    }
    __syncthreads();
  }

  // scores -> LDS (C/D layout: row=(l>>4)*4+r, col=l&15) [m89-verified mapping]
#pragma unroll
  for (int m = 0; m < 4; m++)
#pragma unroll
    for (int n = 0; n < 4; n++)
#pragma unroll
      for (int r = 0; r < 4; r++) {
        int rl = wr * 64 + m * 16 + (l >> 4) * 4 + r;
        int cl = wc * 64 + n * 16 + (l & 15);
        sm.sc[rl * 129 + cl] = acc[m][n][r];
      }
  __syncthreads();

  // parallel top-2: thread t scans 64-col half of row t>>1, then shfl-merge pairs
  {
    int r = t >> 1, h = t & 1;
    float b1 = -1e30f, b2 = -1e30f; int i1 = 0, i2 = 0;
    const float* rowp = &sm.sc[r * 129 + h * 64];
#pragma unroll 8
    for (int j = 0; j < 64; j++) {
      float v = rowp[j];
      int c2 = h * 64 + j;
      if (v > b1) { b2 = b1; i2 = i1; b1 = v; i1 = c2; }
      else if (v > b2) { b2 = v; i2 = c2; }
    }
    float ob1 = __shfl_xor(b1, 1), ob2 = __shfl_xor(b2, 1);
    int oi1 = __shfl_xor(i1, 1), oi2 = __shfl_xor(i2, 1);
    float m1, m2; int j1, j2;
    if (b1 >= ob1) { m1 = b1; j1 = i1; m2 = fmaxf(b2, ob1); j2 = (b2 >= ob1) ? i2 : oi1; }
    else           { m1 = ob1; j1 = oi1; m2 = fmaxf(ob2, b1); j2 = (ob2 >= b1) ? oi2 : i1; }
    if (h == 0) {
      size_t rowg = (size_t)by * BM + r;
      // tile-major layout: contiguous 512B writes per block, no RMW amplification
      pv[(size_t)(bx * 2 + 0) * N_ROWS + rowg] = m1;
      pv[(size_t)(bx * 2 + 1) * N_ROWS + rowg] = m2;
      pi[(size_t)(bx * 2 + 0) * N_ROWS + rowg] = bx * BN + j1;
      pi[(size_t)(bx * 2 + 1) * N_ROWS + rowg] = bx * BN + j2;
    }
  }
}

// ---- per row: pick candidates, rescore in fp32, emit quantized_st + loss + index ----
__global__ void reduce_rescore(
    const float* __restrict__ X, const float* __restrict__ W,
    const float* __restrict__ xnorm, const float* __restrict__ wnorm,
    const float* __restrict__ wn2, const float* __restrict__ pv,
    const int* __restrict__ pi, float* __restrict__ out,
    double* __restrict__ accum, float* __restrict__ outIdx) {
  __shared__ float red[4];
  __shared__ float xnL[DIM];
  __shared__ int candList[NB * 2];
  __shared__ int candCnt;
  int row = blockIdx.x, t = threadIdx.x;

  float v = -1e30f;
  if (t < NB * 2) v = pv[(size_t)t * N_ROWS + row];
  if (t == 0) candCnt = 0;
  float gmax = blockReduceMax256(v, red);   // trailing sync makes candCnt=0 visible
  if (t < NB * 2 && v >= gmax - MARGIN) {
    int p = atomicAdd(&candCnt, 1);
    candList[p] = pi[(size_t)t * N_ROWS + row];
  }
  float xnrm = xnorm[row];
  for (int d = t; d < DIM; d += 256) xnL[d] = X[(size_t)row * DIM + d] / xnrm;
  __syncthreads();

  int cnt = candCnt;
  float bestDist = 1e30f; int bestIdx = 0x7fffffff;
  for (int ci = 0; ci < cnt; ci++) {
    int c = candList[ci];
    float wnr = wnorm[c];
    float part = 0.f;
    for (int d = t; d < DIM; d += 256)
      part += xnL[d] * (W[(size_t)c * DIM + d] / wnr);
    float dot = blockReduceSum256(part, red);
    float dist = wn2[c] - 2.0f * dot;
    if (dist < bestDist || (dist == bestDist && c < bestIdx)) { bestDist = dist; bestIdx = c; }
  }

  int c = bestIdx;
  float wnr = wnorm[c];
  float part = 0.f;
  for (int d = t; d < DIM; d += 256) {
    float q = W[(size_t)c * DIM + d] / wnr;
    float xv = xnL[d];
    out[(size_t)row * DIM + d] = xv + (q - xv);   // straight-through, matches ref fp ops
    float df = q - xv;
    part += df * df;
  }
  float ssum = blockReduceSum256(part, red);
  if (t == 0) {
    atomicAdd(accum, (double)ssum);
    outIdx[row] = (float)c;
  }
}

__global__ void final_loss(const double* __restrict__ accum, float* __restrict__ out) {
  out[0] = (float)(1.25 * accum[0] / (double)((size_t)N_ROWS * DIM));
}

extern "C" void kernel_launch(void* const* d_in, const int* in_sizes, int n_in,
                              void* d_out, int out_size, void* d_ws, size_t ws_size,
                              hipStream_t stream) {
  const float* x = (const float*)d_in[0];
  const float* W = (const float*)d_in[1];
  float* out = (float*)d_out;
  char* ws = (char*)d_ws;

  unsigned short* wn16 = (unsigned short*)(ws);                 //  8 MB
  unsigned short* xn16 = (unsigned short*)(ws + 8388608);       // 32 MB
  float* wnorm = (float*)(ws + 41943040);                       // 32 KB
  float* wn2   = (float*)(ws + 41975808);                       // 32 KB
  float* xnorm = (float*)(ws + 42008576);                       // 128 KB
  float* pv    = (float*)(ws + 42139648);                       // 16 MB
  int*   pi    = (int*)  (ws + 58916864);                       // 16 MB
  double* accum = (double*)(ws + 75694080);                     // 8 B

  hipMemsetAsync(accum, 0, sizeof(double), stream);
  prep_rows<<<K_CODES / 4, 256, 0, stream>>>(W, wn16, wnorm, wn2);
  prep_rows<<<N_ROWS / 4, 256, 0, stream>>>(x, xn16, xnorm, nullptr);
  dim3 grid(NB, N_ROWS / BM);
  gemm_top2<<<grid, 256, 0, stream>>>(xn16, wn16, pv, pi);
  reduce_rescore<<<N_ROWS, 256, 0, stream>>>(
      x, W, xnorm, wnorm, wn2, pv, pi, out, accum,
      out + (size_t)N_ROWS * DIM + 1);
  final_loss<<<1, 1, 0, stream>>>(accum, out + (size_t)N_ROWS * DIM);
}

// Round 5
// 821.184 us; speedup vs baseline: 2.0678x; 1.5224x over previous
//
#include <hip/hip_runtime.h>

#define N_ROWS 32768
#define DIM    512
#define K_CODES 8192
#define BM 128
#define BN 128
#define BK 64
#define NB (K_CODES / BN)   /* 64 code tiles */
#define MARGIN 3e-3f

typedef short s16x8 __attribute__((ext_vector_type(8)));
typedef float f32x4 __attribute__((ext_vector_type(4)));

__device__ __forceinline__ unsigned short f2bf(float f) {
  unsigned int u = __float_as_uint(f);
  u = (u + 0x7fffu + ((u >> 16) & 1u)) >> 16;   // RNE
  return (unsigned short)u;
}

__device__ __forceinline__ void gload_lds16(const void* g, void* l) {
  __builtin_amdgcn_global_load_lds(
      (const __attribute__((address_space(1))) void*)g,
      (__attribute__((address_space(3))) void*)l,
      16, 0, 0);
}

// merge candidate ordered pair (c1,ci1)>=(c2,ci2) into running top-2 with min-idx tie-break
__device__ __forceinline__ void top2merge(float& b1, int& i1, float& b2, int& i2,
                                          float c1, int ci1, float c2, int ci2) {
  if (c1 > b1 || (c1 == b1 && ci1 < i1)) {
    b2 = b1; i2 = i1; b1 = c1; i1 = ci1;
    if (c2 > b2 || (c2 == b2 && ci2 < i2)) { b2 = c2; i2 = ci2; }
  } else {
    if (c1 > b2 || (c1 == b2 && ci1 < i2)) { b2 = c1; i2 = ci1; }
    if (c2 > b2 || (c2 == b2 && ci2 < i2)) { b2 = c2; i2 = ci2; }
  }
}

// ---- wave-per-row normalize: 4 rows/block, float4x2 per lane, no syncthreads ----
__global__ void prep_rows(const float* __restrict__ src, unsigned short* __restrict__ dst16,
                          float* __restrict__ norms, float* __restrict__ sq) {
  int row = blockIdx.x * 4 + (threadIdx.x >> 6);
  int l = threadIdx.x & 63;
  const float4* p = (const float4*)&src[(size_t)row * DIM + l * 8];
  float4 v0 = p[0], v1 = p[1];
  float ss = v0.x * v0.x + v0.y * v0.y + v0.z * v0.z + v0.w * v0.w
           + v1.x * v1.x + v1.y * v1.y + v1.z * v1.z + v1.w * v1.w;
#pragma unroll
  for (int o = 32; o; o >>= 1) ss += __shfl_xor(ss, o);
  float nrm = fmaxf(sqrtf(ss), 1e-12f);
  float q[8];
  q[0] = v0.x / nrm; q[1] = v0.y / nrm; q[2] = v0.z / nrm; q[3] = v0.w / nrm;
  q[4] = v1.x / nrm; q[5] = v1.y / nrm; q[6] = v1.z / nrm; q[7] = v1.w / nrm;
  s16x8 b;
#pragma unroll
  for (int j = 0; j < 8; j++) b[j] = (short)f2bf(q[j]);
  *(s16x8*)&dst16[(size_t)row * DIM + l * 8] = b;
  if (sq) {
    float s2 = q[0]*q[0] + q[1]*q[1] + q[2]*q[2] + q[3]*q[3]
             + q[4]*q[4] + q[5]*q[5] + q[6]*q[6] + q[7]*q[7];
#pragma unroll
    for (int o = 32; o; o >>= 1) s2 += __shfl_xor(s2, o);
    if (l == 0) sq[row] = s2;
  }
  if (l == 0) norms[row] = nrm;
}

// ---- bf16 MFMA GEMM (scores = xn.wn^T), XOR-swizzled LDS, in-register top-2 ----
__global__ __launch_bounds__(256, 4) void gemm_top2(
    const unsigned short* __restrict__ xn16, const unsigned short* __restrict__ wn16,
    float* __restrict__ pv, int* __restrict__ pi) {
  union SMem {
    struct { unsigned short A[BM * BK]; unsigned short B[BN * BK]; } st;  // 32 KB
    float4 halfRes[2][BM];                                                // 4 KB
  };
  __shared__ SMem sm;
  int bx = blockIdx.x;              // code tile 0..63
  int by = blockIdx.y;              // row tile 0..255
  int t = threadIdx.x;
  int w = t >> 6, l = t & 63;
  int wr = w >> 1, wc = w & 1;      // wave quadrant (64x64)
  int rr = l & 15, hi = l >> 4;
  f32x4 acc[4][4] = {};

  const unsigned short* Ab = xn16 + (size_t)by * BM * DIM;
  const unsigned short* Bb = wn16 + (size_t)bx * BN * DIM;

  for (int k0 = 0; k0 < DIM; k0 += BK) {
    // stage 128x64 tiles; LDS linear dest, XOR-swizzled global source (rule #21)
#pragma unroll
    for (int i = 0; i < 4; i++) {
      int c = i * 256 + t;          // chunk 0..1023 (16B each)
      int r = c >> 3, sl = c & 7;
      int sg = sl ^ (r & 7);        // source slot: same involution as the read
      gload_lds16(Ab + (size_t)r * DIM + k0 + sg * 8, &sm.st.A[c * 8]);
      gload_lds16(Bb + (size_t)r * DIM + k0 + sg * 8, &sm.st.B[c * 8]);
    }
    __syncthreads();                // compiler drains vmcnt before s_barrier

#pragma unroll
    for (int ks = 0; ks < 2; ks++) {
      s16x8 aF[4], bF[4];
      int s = ks * 4 + hi;          // 16B slot within 128B row
#pragma unroll
      for (int m = 0; m < 4; m++) {
        int row = wr * 64 + m * 16 + rr;
        aF[m] = *(const s16x8*)&sm.st.A[row * BK + ((s ^ (row & 7)) * 8)];
      }
#pragma unroll
      for (int n = 0; n < 4; n++) {
        int row = wc * 64 + n * 16 + rr;
        bF[n] = *(const s16x8*)&sm.st.B[row * BK + ((s ^ (row & 7)) * 8)];
      }
#pragma unroll
      for (int m = 0; m < 4; m++)
#pragma unroll
        for (int n = 0; n < 4; n++)
          acc[m][n] = __builtin_amdgcn_mfma_f32_16x16x32_bf16(aF[m], bF[n], acc[m][n], 0, 0, 0);
    }
    __syncthreads();
  }

  // -------- in-register top-2 over this wave's 64x64 half-tile --------
  // C/D layout: element r of acc[m][n] -> row wr*64+m*16+hi*4+r, col wc*64+n*16+rr
  float fv1 = -1e30f, fv2 = -1e30f; int fi1 = 0, fi2 = 0;
#pragma unroll
  for (int m = 0; m < 4; m++) {
#pragma unroll
    for (int r = 0; r < 4; r++) {
      float b1 = -1e30f, b2 = -1e30f; int i1 = 0x7fffffff, i2 = 0x7fffffff;
#pragma unroll
      for (int n = 0; n < 4; n++) {
        float v = acc[m][n][r];
        int col = wc * 64 + n * 16 + rr;
        if (v > b1) { b2 = b1; i2 = i1; b1 = v; i1 = col; }
        else if (v > b2) { b2 = v; i2 = col; }
      }
      // merge across the 16-lane group sharing hi (lanes hi*16..hi*16+15)
#pragma unroll
      for (int off = 1; off < 16; off <<= 1) {
        float ob1 = __shfl_xor(b1, off), ob2 = __shfl_xor(b2, off);
        int oi1 = __shfl_xor(i1, off), oi2 = __shfl_xor(i2, off);
        top2merge(b1, i1, b2, i2, ob1, oi1, ob2, oi2);
      }
      if (rr == m * 4 + r) { fv1 = b1; fi1 = i1; fv2 = b2; fi2 = i2; }
    }
  }
  // each lane now owns one row's half-top2: row_local = wr*64 + (rr>>2)*16 + hi*4 + (rr&3)
  int row_local = wr * 64 + (rr >> 2) * 16 + hi * 4 + (rr & 3);
  sm.halfRes[wc][row_local] = make_float4(fv1, __int_as_float(fi1), fv2, __int_as_float(fi2));
  __syncthreads();

  if (t < BM) {
    float4 h0 = sm.halfRes[0][t], h1 = sm.halfRes[1][t];
    float b1 = h0.x, b2 = h0.z; int i1 = __float_as_int(h0.y), i2 = __float_as_int(h0.w);
    top2merge(b1, i1, b2, i2, h1.x, __float_as_int(h1.y), h1.z, __float_as_int(h1.w));
    size_t rowg = (size_t)by * BM + t;
    pv[(size_t)(bx * 2 + 0) * N_ROWS + rowg] = b1;
    pv[(size_t)(bx * 2 + 1) * N_ROWS + rowg] = b2;
    pi[(size_t)(bx * 2 + 0) * N_ROWS + rowg] = bx * BN + i1;
    pi[(size_t)(bx * 2 + 1) * N_ROWS + rowg] = bx * BN + i2;
  }
}

// ---- wave-per-row: pick candidates, rescore fp32, emit quantized_st + partial loss ----
__global__ void reduce_rescore(
    const float* __restrict__ X, const float* __restrict__ W,
    const float* __restrict__ xnorm, const float* __restrict__ wnorm,
    const float* __restrict__ wn2, const float* __restrict__ pv,
    const int* __restrict__ pi, float* __restrict__ out,
    float* __restrict__ partial, float* __restrict__ outIdx) {
  int row = blockIdx.x * 4 + (threadIdx.x >> 6);
  int l = threadIdx.x & 63;

  float xnrm = xnorm[row];
  const float4* xp = (const float4*)&X[(size_t)row * DIM + l * 8];
  float4 a0 = xp[0], a1 = xp[1];
  float xq[8];
  xq[0] = a0.x / xnrm; xq[1] = a0.y / xnrm; xq[2] = a0.z / xnrm; xq[3] = a0.w / xnrm;
  xq[4] = a1.x / xnrm; xq[5] = a1.y / xnrm; xq[6] = a1.z / xnrm; xq[7] = a1.w / xnrm;

  // candidate slots: lane l owns slots 2l, 2l+1 of the 128 per-tile top-2 entries
  float v0 = pv[(size_t)(2 * l) * N_ROWS + row];
  float v1 = pv[(size_t)(2 * l + 1) * N_ROWS + row];
  float mx = fmaxf(v0, v1);
#pragma unroll
  for (int o = 32; o; o >>= 1) mx = fmaxf(mx, __shfl_xor(mx, o));
  float thr = mx - MARGIN;
  unsigned long long mask0 = __ballot(v0 >= thr);
  unsigned long long mask1 = __ballot(v1 >= thr);
  int c0 = (v0 >= thr) ? pi[(size_t)(2 * l) * N_ROWS + row] : 0;
  int c1 = (v1 >= thr) ? pi[(size_t)(2 * l + 1) * N_ROWS + row] : 0;

  float bestDist = 1e30f; int bestIdx = 0x7fffffff;
  while (mask0 | mask1) {
    int c;
    if (mask0) {
      int ln = __ffsll((unsigned long long)mask0) - 1; mask0 &= mask0 - 1;
      c = __shfl(c0, ln);
    } else {
      int ln = __ffsll((unsigned long long)mask1) - 1; mask1 &= mask1 - 1;
      c = __shfl(c1, ln);
    }
    float wnr = wnorm[c];
    const float4* wp = (const float4*)&W[(size_t)c * DIM + l * 8];
    float4 w0 = wp[0], w1 = wp[1];
    float d = xq[0] * (w0.x / wnr) + xq[1] * (w0.y / wnr)
            + xq[2] * (w0.z / wnr) + xq[3] * (w0.w / wnr)
            + xq[4] * (w1.x / wnr) + xq[5] * (w1.y / wnr)
            + xq[6] * (w1.z / wnr) + xq[7] * (w1.w / wnr);
#pragma unroll
    for (int o = 32; o; o >>= 1) d += __shfl_xor(d, o);
    float dist = wn2[c] - 2.0f * d;
    if (dist < bestDist || (dist == bestDist && c < bestIdx)) { bestDist = dist; bestIdx = c; }
  }

  int c = bestIdx;
  float wnr = wnorm[c];
  const float4* wp = (const float4*)&W[(size_t)c * DIM + l * 8];
  float4 w0 = wp[0], w1 = wp[1];
  float q[8];
  q[0] = w0.x / wnr; q[1] = w0.y / wnr; q[2] = w0.z / wnr; q[3] = w0.w / wnr;
  q[4] = w1.x / wnr; q[5] = w1.y / wnr; q[6] = w1.z / wnr; q[7] = w1.w / wnr;
  float4 o0, o1;
  o0.x = xq[0] + (q[0] - xq[0]); o0.y = xq[1] + (q[1] - xq[1]);
  o0.z = xq[2] + (q[2] - xq[2]); o0.w = xq[3] + (q[3] - xq[3]);
  o1.x = xq[4] + (q[4] - xq[4]); o1.y = xq[5] + (q[5] - xq[5]);
  o1.z = xq[6] + (q[6] - xq[6]); o1.w = xq[7] + (q[7] - xq[7]);
  float4* op = (float4*)&out[(size_t)row * DIM + l * 8];
  op[0] = o0; op[1] = o1;
  float ssum = 0.f;
#pragma unroll
  for (int j = 0; j < 8; j++) { float df = q[j] - xq[j]; ssum += df * df; }
#pragma unroll
  for (int o = 32; o; o >>= 1) ssum += __shfl_xor(ssum, o);
  if (l == 0) { partial[row] = ssum; outIdx[row] = (float)c; }
}

__global__ void final_loss(const float* __restrict__ partial, float* __restrict__ out) {
  __shared__ double red[4];
  int t = threadIdx.x;
  double s = 0.0;
  for (int i = t; i < N_ROWS; i += 256) s += (double)partial[i];
#pragma unroll
  for (int o = 32; o; o >>= 1) s += __shfl_xor(s, o);
  if ((t & 63) == 0) red[t >> 6] = s;
  __syncthreads();
  if (t == 0)
    out[0] = (float)(1.25 * (red[0] + red[1] + red[2] + red[3]) /
                     (double)((size_t)N_ROWS * DIM));
}

extern "C" void kernel_launch(void* const* d_in, const int* in_sizes, int n_in,
                              void* d_out, int out_size, void* d_ws, size_t ws_size,
                              hipStream_t stream) {
  const float* x = (const float*)d_in[0];
  const float* W = (const float*)d_in[1];
  float* out = (float*)d_out;
  char* ws = (char*)d_ws;

  unsigned short* wn16 = (unsigned short*)(ws);                 //  8 MB
  unsigned short* xn16 = (unsigned short*)(ws + 8388608);       // 32 MB
  float* wnorm = (float*)(ws + 41943040);                       // 32 KB
  float* wn2   = (float*)(ws + 41975808);                       // 32 KB
  float* xnorm = (float*)(ws + 42008576);                       // 128 KB
  float* pv    = (float*)(ws + 42139648);                       // 16 MB
  int*   pi    = (int*)  (ws + 58916864);                       // 16 MB
  // partial loss sums: reuse xn16 region (xn16 dead after gemm_top2)
  float* partial = (float*)(ws + 8388608);

  prep_rows<<<K_CODES / 4, 256, 0, stream>>>(W, wn16, wnorm, wn2);
  prep_rows<<<N_ROWS / 4, 256, 0, stream>>>(x, xn16, xnorm, nullptr);
  dim3 grid(NB, N_ROWS / BM);
  gemm_top2<<<grid, 256, 0, stream>>>(xn16, wn16, pv, pi);
  reduce_rescore<<<N_ROWS / 4, 256, 0, stream>>>(
      x, W, xnorm, wnorm, wn2, pv, pi, out, partial,
      out + (size_t)N_ROWS * DIM + 1);
  final_loss<<<1, 256, 0, stream>>>(partial, out + (size_t)N_ROWS * DIM);
}

// Round 6
// 687.966 us; speedup vs baseline: 2.4682x; 1.1936x over previous
//
#include <hip/hip_runtime.h>

#define N_ROWS 32768
#define DIM    512
#define K_CODES 8192
#define BM 128
#define BN 128
#define BK 64
#define NB (K_CODES / BN)   /* 64 code tiles */
#define MARGIN 3e-3f

typedef short s16x8 __attribute__((ext_vector_type(8)));
typedef float f32x4 __attribute__((ext_vector_type(4)));
typedef unsigned long long u64;

__device__ __forceinline__ unsigned short f2bf(float f) {
  unsigned int u = __float_as_uint(f);
  u = (u + 0x7fffu + ((u >> 16) & 1u)) >> 16;   // RNE
  return (unsigned short)u;
}

// order-preserving float->u32 (monotonic unsigned compare)
__device__ __forceinline__ unsigned int ordf(float f) {
  unsigned int u = __float_as_uint(f);
  return (u & 0x80000000u) ? ~u : (u | 0x80000000u);
}
__device__ __forceinline__ float unordf(unsigned int o) {
  return (o & 0x80000000u) ? __uint_as_float(o ^ 0x80000000u) : __uint_as_float(~o);
}

__device__ __forceinline__ void gload_lds16(const void* g, void* l) {
  __builtin_amdgcn_global_load_lds(
      (const __attribute__((address_space(1))) void*)g,
      (__attribute__((address_space(3))) void*)l,
      16, 0, 0);
}

// ---- unified normalize: blocks [0,2048) -> W rows, [2048,10240) -> X rows ----
__global__ void prep_all(const float* __restrict__ W, const float* __restrict__ X,
                         unsigned short* __restrict__ wn16, unsigned short* __restrict__ xn16,
                         float* __restrict__ wnorm, float* __restrict__ wn2,
                         float* __restrict__ xnorm) {
  int b = blockIdx.x;
  bool isW = b < (K_CODES / 4);
  int row = (isW ? b : b - K_CODES / 4) * 4 + (threadIdx.x >> 6);
  int l = threadIdx.x & 63;
  const float* src = isW ? W : X;
  const float4* p = (const float4*)&src[(size_t)row * DIM + l * 8];
  float4 v0 = p[0], v1 = p[1];
  float ss = v0.x * v0.x + v0.y * v0.y + v0.z * v0.z + v0.w * v0.w
           + v1.x * v1.x + v1.y * v1.y + v1.z * v1.z + v1.w * v1.w;
#pragma unroll
  for (int o = 32; o; o >>= 1) ss += __shfl_xor(ss, o);
  float nrm = fmaxf(sqrtf(ss), 1e-12f);
  float q[8];
  q[0] = v0.x / nrm; q[1] = v0.y / nrm; q[2] = v0.z / nrm; q[3] = v0.w / nrm;
  q[4] = v1.x / nrm; q[5] = v1.y / nrm; q[6] = v1.z / nrm; q[7] = v1.w / nrm;
  s16x8 bv;
#pragma unroll
  for (int j = 0; j < 8; j++) bv[j] = (short)f2bf(q[j]);
  unsigned short* dst = isW ? wn16 : xn16;
  *(s16x8*)&dst[(size_t)row * DIM + l * 8] = bv;
  if (isW) {
    float s2 = q[0]*q[0] + q[1]*q[1] + q[2]*q[2] + q[3]*q[3]
             + q[4]*q[4] + q[5]*q[5] + q[6]*q[6] + q[7]*q[7];
#pragma unroll
    for (int o = 32; o; o >>= 1) s2 += __shfl_xor(s2, o);
    if (l == 0) { wnorm[row] = nrm; wn2[row] = s2; }
  } else {
    if (l == 0) xnorm[row] = nrm;
  }
}

// ---- bf16 MFMA GEMM + in-register scan + LDS-merge top-2 ----
__global__ __launch_bounds__(256, 4) void gemm_top2(
    const unsigned short* __restrict__ xn16, const unsigned short* __restrict__ wn16,
    float* __restrict__ pv, int* __restrict__ pi) {
  union SMem {
    struct { unsigned short A[BM * BK]; unsigned short B[BN * BK]; } st;  // 32 KB
    uint4 ep[64 * 33];                                                    // 33.8 KB
  };
  __shared__ SMem sm;
  int bx = blockIdx.x;              // code tile 0..63
  int by = blockIdx.y;              // row tile 0..255
  int t = threadIdx.x;
  int w = t >> 6, l = t & 63;
  int wr = w >> 1, wc = w & 1;      // wave quadrant (64x64)
  int rr = l & 15, hi = l >> 4;
  f32x4 acc[4][4] = {};

  const unsigned short* Ab = xn16 + (size_t)by * BM * DIM;
  const unsigned short* Bb = wn16 + (size_t)bx * BN * DIM;

  // hoisted staging pointers (4 A-chunks + 4 B-chunks per thread per k-step)
  const unsigned short* pA[4];
  const unsigned short* pB[4];
#pragma unroll
  for (int i = 0; i < 4; i++) {
    int c = i * 256 + t;            // chunk 0..1023 (16B each)
    int r = c >> 3, sl = c & 7;
    int sg = sl ^ (r & 7);          // source slot: same involution as the read
    pA[i] = Ab + (size_t)r * DIM + sg * 8;
    pB[i] = Bb + (size_t)r * DIM + sg * 8;
  }
  // hoisted LDS fragment offsets (k0-invariant)
  int aoff[2][4], boff[2][4];
#pragma unroll
  for (int ks = 0; ks < 2; ks++)
#pragma unroll
    for (int m = 0; m < 4; m++) {
      int ra = wr * 64 + m * 16 + rr;
      int rb = wc * 64 + m * 16 + rr;
      int s = ks * 4 + hi;
      aoff[ks][m] = ra * BK + ((s ^ (ra & 7)) * 8);
      boff[ks][m] = rb * BK + ((s ^ (rb & 7)) * 8);
    }

  for (int k0 = 0; k0 < DIM; k0 += BK) {
#pragma unroll
    for (int i = 0; i < 4; i++) {
      int c = i * 256 + t;
      gload_lds16(pA[i], &sm.st.A[c * 8]);
      gload_lds16(pB[i], &sm.st.B[c * 8]);
      pA[i] += BK; pB[i] += BK;
    }
    __syncthreads();                // drains vmcnt before LDS reads

#pragma unroll
    for (int ks = 0; ks < 2; ks++) {
      s16x8 aF[4], bF[4];
#pragma unroll
      for (int m = 0; m < 4; m++) aF[m] = *(const s16x8*)&sm.st.A[aoff[ks][m]];
#pragma unroll
      for (int n = 0; n < 4; n++) bF[n] = *(const s16x8*)&sm.st.B[boff[ks][n]];
#pragma unroll
      for (int m = 0; m < 4; m++)
#pragma unroll
        for (int n = 0; n < 4; n++)
          acc[m][n] = __builtin_amdgcn_mfma_f32_16x16x32_bf16(aF[m], bF[n], acc[m][n], 0, 0, 0);
    }
    __syncthreads();
  }

  // ======== epilogue: scan -> LDS merge (two row-half passes) ========
  // C/D layout: acc[m][n][r] -> row wr*64+m*16+hi*4+r, col wc*64+n*16+rr
  int wcbase = wc * 64;

  auto scan_write = [&]() {
#pragma unroll
    for (int m = 0; m < 4; m++)
#pragma unroll
      for (int r = 0; r < 4; r++) {
        float v0 = acc[m][0][r], v1 = acc[m][1][r], v2 = acc[m][2][r], v3 = acc[m][3][r];
        // top2-of-4 (col order 0<1<2<3; ties keep lower col)
        float a1, a2, d1, d2, t1, t2; int i1, i2, j1, j2, u1, u2;
        if (v1 > v0) { a1 = v1; i1 = 1; a2 = v0; i2 = 0; } else { a1 = v0; i1 = 0; a2 = v1; i2 = 1; }
        if (v3 > v2) { d1 = v3; j1 = 3; d2 = v2; j2 = 2; } else { d1 = v2; j1 = 2; d2 = v3; j2 = 3; }
        if (a1 >= d1) { t1 = a1; u1 = i1; if (d1 > a2) { t2 = d1; u2 = j1; } else { t2 = a2; u2 = i2; } }
        else          { t1 = d1; u1 = j1; if (a1 >= d2) { t2 = a1; u2 = i1; } else { t2 = d2; u2 = j2; } }
        int col1 = wcbase + u1 * 16 + rr, col2 = wcbase + u2 * 16 + rr;
        u64 k1 = ((u64)ordf(t1) << 32) | (unsigned)(~col1);
        u64 k2 = ((u64)ordf(t2) << 32) | (unsigned)(~col2);
        int rloc = m * 16 + hi * 4 + r;          // 0..63 within this wr half
        int e = wc * 16 + rr;                    // 0..31
        int slot = (e + rloc) & 31;
        sm.ep[rloc * 33 + slot] =
            make_uint4((unsigned)k1, (unsigned)(k1 >> 32), (unsigned)k2, (unsigned)(k2 >> 32));
      }
  };

  auto finalize_store = [&](int pass) {
    u64 K1 = 0, K2 = 0;
#pragma unroll 4
    for (int e = 0; e < 32; e++) {
      uint4 qq = sm.ep[t * 33 + ((e + t) & 31)];
      u64 e1 = ((u64)qq.y << 32) | qq.x;
      u64 e2 = ((u64)qq.w << 32) | qq.z;
      if (e1 > K1) { K2 = (K1 > e2) ? K1 : e2; K1 = e1; }
      else if (e1 > K2) { K2 = e1; }
    }
    int rowl = pass * 64 + t;
    size_t rowg = (size_t)by * BM + rowl;
    float f1 = unordf((unsigned)(K1 >> 32));
    float f2 = unordf((unsigned)(K2 >> 32));
    int c1 = (int)(~(unsigned)K1);
    int c2 = (int)(~(unsigned)K2);
    pv[(size_t)(bx * 2 + 0) * N_ROWS + rowg] = f1;
    pv[(size_t)(bx * 2 + 1) * N_ROWS + rowg] = f2;
    pi[(size_t)(bx * 2 + 0) * N_ROWS + rowg] = bx * BN + c1;
    pi[(size_t)(bx * 2 + 1) * N_ROWS + rowg] = bx * BN + c2;
  };

  if (wr == 0) scan_write();
  __syncthreads();
  if (t < 64) finalize_store(0);
  __syncthreads();
  if (wr == 1) scan_write();
  __syncthreads();
  if (t < 64) finalize_store(1);
}

// ---- collapse: per-row max over 128 entries + candidate list (argmax first) ----
__global__ void collapse(const float* __restrict__ pv, const int* __restrict__ pi,
                         int* __restrict__ cand) {
  int r = blockIdx.x * 256 + threadIdx.x;
  float mx = -1e30f; int be = 0;
#pragma unroll 8
  for (int e = 0; e < 2 * NB; e++) {
    float v = pv[(size_t)e * N_ROWS + r];
    if (v > mx) { mx = v; be = e; }
  }
  float thr = mx - MARGIN;
  cand[r * 8 + 1] = pi[(size_t)be * N_ROWS + r];
  int cnt = 1;
  for (int e = 0; e < 2 * NB; e++) {
    if (e == be) continue;
    float v = pv[(size_t)e * N_ROWS + r];
    if (v >= thr && cnt < 7) { cand[r * 8 + 1 + cnt] = pi[(size_t)e * N_ROWS + r]; cnt++; }
  }
  cand[r * 8] = cnt;
}

// ---- wave-per-row: rescore candidates fp32, emit quantized_st + partial loss ----
__global__ void reduce_rescore(
    const float* __restrict__ X, const float* __restrict__ W,
    const float* __restrict__ xnorm, const float* __restrict__ wnorm,
    const float* __restrict__ wn2, const int* __restrict__ cand,
    float* __restrict__ out, float* __restrict__ partial, float* __restrict__ outIdx) {
  int row = blockIdx.x * 4 + (threadIdx.x >> 6);
  int l = threadIdx.x & 63;

  float xnrm = xnorm[row];
  const float4* xp = (const float4*)&X[(size_t)row * DIM + l * 8];
  float4 a0 = xp[0], a1 = xp[1];
  float xq[8];
  xq[0] = a0.x / xnrm; xq[1] = a0.y / xnrm; xq[2] = a0.z / xnrm; xq[3] = a0.w / xnrm;
  xq[4] = a1.x / xnrm; xq[5] = a1.y / xnrm; xq[6] = a1.z / xnrm; xq[7] = a1.w / xnrm;

  int cnt = cand[row * 8];
  float bestDist = 1e30f; int bestIdx = 0x7fffffff;
  for (int ci = 0; ci < cnt; ci++) {
    int c = cand[row * 8 + 1 + ci];
    float wnr = wnorm[c];
    const float4* wp = (const float4*)&W[(size_t)c * DIM + l * 8];
    float4 w0 = wp[0], w1 = wp[1];
    float d = xq[0] * (w0.x / wnr) + xq[1] * (w0.y / wnr)
            + xq[2] * (w0.z / wnr) + xq[3] * (w0.w / wnr)
            + xq[4] * (w1.x / wnr) + xq[5] * (w1.y / wnr)
            + xq[6] * (w1.z / wnr) + xq[7] * (w1.w / wnr);
#pragma unroll
    for (int o = 32; o; o >>= 1) d += __shfl_xor(d, o);
    float dist = wn2[c] - 2.0f * d;
    if (dist < bestDist || (dist == bestDist && c < bestIdx)) { bestDist = dist; bestIdx = c; }
  }

  int c = bestIdx;
  float wnr = wnorm[c];
  const float4* wp = (const float4*)&W[(size_t)c * DIM + l * 8];
  float4 w0 = wp[0], w1 = wp[1];
  float q[8];
  q[0] = w0.x / wnr; q[1] = w0.y / wnr; q[2] = w0.z / wnr; q[3] = w0.w / wnr;
  q[4] = w1.x / wnr; q[5] = w1.y / wnr; q[6] = w1.z / wnr; q[7] = w1.w / wnr;
  float4 o0, o1;
  o0.x = xq[0] + (q[0] - xq[0]); o0.y = xq[1] + (q[1] - xq[1]);
  o0.z = xq[2] + (q[2] - xq[2]); o0.w = xq[3] + (q[3] - xq[3]);
  o1.x = xq[4] + (q[4] - xq[4]); o1.y = xq[5] + (q[5] - xq[5]);
  o1.z = xq[6] + (q[6] - xq[6]); o1.w = xq[7] + (q[7] - xq[7]);
  float4* op = (float4*)&out[(size_t)row * DIM + l * 8];
  op[0] = o0; op[1] = o1;
  float ssum = 0.f;
#pragma unroll
  for (int j = 0; j < 8; j++) { float df = q[j] - xq[j]; ssum += df * df; }
#pragma unroll
  for (int o = 32; o; o >>= 1) ssum += __shfl_xor(ssum, o);
  if (l == 0) { partial[row] = ssum; outIdx[row] = (float)c; }
}

// ---- loss reduction: 128 blocks, one elem/thread, wave-reduce + atomic ----
__global__ void reduce_loss(const float* __restrict__ partial, float* __restrict__ accum) {
  int i = blockIdx.x * 256 + threadIdx.x;
  float s = partial[i];
#pragma unroll
  for (int o = 32; o; o >>= 1) s += __shfl_xor(s, o);
  if ((threadIdx.x & 63) == 0) atomicAdd(accum, s);
}

__global__ void write_loss(const float* __restrict__ accum, float* __restrict__ out) {
  out[0] = (float)(1.25 * (double)accum[0] / (double)((size_t)N_ROWS * DIM));
}

extern "C" void kernel_launch(void* const* d_in, const int* in_sizes, int n_in,
                              void* d_out, int out_size, void* d_ws, size_t ws_size,
                              hipStream_t stream) {
  const float* x = (const float*)d_in[0];
  const float* W = (const float*)d_in[1];
  float* out = (float*)d_out;
  char* ws = (char*)d_ws;

  unsigned short* wn16 = (unsigned short*)(ws);                 //  8 MB
  unsigned short* xn16 = (unsigned short*)(ws + 8388608);       // 32 MB (dead after gemm)
  float* wnorm = (float*)(ws + 41943040);                       // 32 KB
  float* wn2   = (float*)(ws + 41975808);                       // 32 KB
  float* xnorm = (float*)(ws + 42008576);                       // 128 KB
  float* pv    = (float*)(ws + 42139648);                       // 16 MB
  int*   pi    = (int*)  (ws + 58916864);                       // 16 MB
  float* accum = (float*)(ws + 75694080);                       // 4 B
  // these reuse the dead xn16 region (only written after gemm_top2):
  float* partial = (float*)(ws + 8388608);                      // 128 KB
  int*   cand    = (int*)  (ws + 8519680);                      // 1 MB

  hipMemsetAsync(accum, 0, sizeof(float), stream);
  prep_all<<<K_CODES / 4 + N_ROWS / 4, 256, 0, stream>>>(W, x, wn16, xn16, wnorm, wn2, xnorm);
  dim3 grid(NB, N_ROWS / BM);
  gemm_top2<<<grid, 256, 0, stream>>>(xn16, wn16, pv, pi);
  collapse<<<N_ROWS / 256, 256, 0, stream>>>(pv, pi, cand);
  reduce_rescore<<<N_ROWS / 4, 256, 0, stream>>>(
      x, W, xnorm, wnorm, wn2, cand, out, partial,
      out + (size_t)N_ROWS * DIM + 1);
  reduce_loss<<<N_ROWS / 256, 256, 0, stream>>>(partial, accum);
  write_loss<<<1, 1, 0, stream>>>(accum, out + (size_t)N_ROWS * DIM);
}

// Round 7
// 591.393 us; speedup vs baseline: 2.8712x; 1.1633x over previous
//
#include <hip/hip_runtime.h>

#define N_ROWS 32768
#define DIM    512
#define K_CODES 8192
#define BM 128
#define BN 128
#define BK 64
#define NB (K_CODES / BN)   /* 64 code tiles */
#define MARGIN 3e-3f

typedef short s16x8 __attribute__((ext_vector_type(8)));
typedef float f32x4 __attribute__((ext_vector_type(4)));
typedef unsigned long long u64;

__device__ __forceinline__ unsigned short f2bf(float f) {
  unsigned int u = __float_as_uint(f);
  u = (u + 0x7fffu + ((u >> 16) & 1u)) >> 16;   // RNE
  return (unsigned short)u;
}

// order-preserving float->u32 (monotonic unsigned compare)
__device__ __forceinline__ unsigned int ordf(float f) {
  unsigned int u = __float_as_uint(f);
  return (u & 0x80000000u) ? ~u : (u | 0x80000000u);
}
__device__ __forceinline__ float unordf(unsigned int o) {
  return (o & 0x80000000u) ? __uint_as_float(o ^ 0x80000000u) : __uint_as_float(~o);
}

__device__ __forceinline__ void gload_lds16(const void* g, void* l) {
  __builtin_amdgcn_global_load_lds(
      (const __attribute__((address_space(1))) void*)g,
      (__attribute__((address_space(3))) void*)l,
      16, 0, 0);
}

// ---- unified normalize: blocks [0,2048) -> W rows, [2048,10240) -> X rows ----
__global__ void prep_all(const float* __restrict__ W, const float* __restrict__ X,
                         unsigned short* __restrict__ wn16, unsigned short* __restrict__ xn16,
                         float* __restrict__ wnorm, float* __restrict__ wn2,
                         float* __restrict__ xnorm) {
  int b = blockIdx.x;
  bool isW = b < (K_CODES / 4);
  int row = (isW ? b : b - K_CODES / 4) * 4 + (threadIdx.x >> 6);
  int l = threadIdx.x & 63;
  const float* src = isW ? W : X;
  const float4* p = (const float4*)&src[(size_t)row * DIM + l * 8];
  float4 v0 = p[0], v1 = p[1];
  float ss = v0.x * v0.x + v0.y * v0.y + v0.z * v0.z + v0.w * v0.w
           + v1.x * v1.x + v1.y * v1.y + v1.z * v1.z + v1.w * v1.w;
#pragma unroll
  for (int o = 32; o; o >>= 1) ss += __shfl_xor(ss, o);
  float nrm = fmaxf(sqrtf(ss), 1e-12f);
  float q[8];
  q[0] = v0.x / nrm; q[1] = v0.y / nrm; q[2] = v0.z / nrm; q[3] = v0.w / nrm;
  q[4] = v1.x / nrm; q[5] = v1.y / nrm; q[6] = v1.z / nrm; q[7] = v1.w / nrm;
  s16x8 bv;
#pragma unroll
  for (int j = 0; j < 8; j++) bv[j] = (short)f2bf(q[j]);
  unsigned short* dst = isW ? wn16 : xn16;
  *(s16x8*)&dst[(size_t)row * DIM + l * 8] = bv;
  if (isW) {
    float s2 = q[0]*q[0] + q[1]*q[1] + q[2]*q[2] + q[3]*q[3]
             + q[4]*q[4] + q[5]*q[5] + q[6]*q[6] + q[7]*q[7];
#pragma unroll
    for (int o = 32; o; o >>= 1) s2 += __shfl_xor(s2, o);
    if (l == 0) { wnorm[row] = nrm; wn2[row] = s2; }
  } else {
    if (l == 0) xnorm[row] = nrm;
  }
}

// ---- bf16 MFMA GEMM + in-register scan + LDS-merge top-2 ----
__global__ __launch_bounds__(256, 4) void gemm_top2(
    const unsigned short* __restrict__ xn16, const unsigned short* __restrict__ wn16,
    float* __restrict__ pv, int* __restrict__ pi) {
  union SMem {
    struct { unsigned short A[BM * BK]; unsigned short B[BN * BK]; } st;  // 32 KB
    uint4 ep[64 * 33];                                                    // 33.8 KB
  };
  __shared__ SMem sm;
  int bx = blockIdx.x;              // code tile 0..63
  int by = blockIdx.y;              // row tile 0..255
  int t = threadIdx.x;
  int w = t >> 6, l = t & 63;
  int wr = w >> 1, wc = w & 1;      // wave quadrant (64x64)
  int rr = l & 15, hi = l >> 4;
  f32x4 acc[4][4] = {};

  // staging: chunk i covers row i*32 + (t>>3); XOR slot sg = (t&7)^((t>>3)&7)
  // is i-invariant, so chunk i's address = base + i*32768 bytes. 2 ptrs total.
  int srow = t >> 3;
  int sg = (t & 7) ^ (srow & 7);
  const unsigned short* aP = xn16 + (size_t)by * BM * DIM + (size_t)srow * DIM + sg * 8;
  const unsigned short* bP = wn16 + (size_t)bx * BN * DIM + (size_t)srow * DIM + sg * 8;

  // LDS read bases (elements). row&7 == rr&7 since m*16, wr*64 are mult of 8,
  // so the m-term is a pure +m*1024 imm and ks=1 base is ks=0 base ^ 32.
  int aB0 = (wr * 64 + rr) * BK + ((hi ^ (rr & 7)) * 8);
  int bB0 = (wc * 64 + rr) * BK + ((hi ^ (rr & 7)) * 8);

  for (int k0 = 0; k0 < DIM; k0 += BK) {
#pragma unroll
    for (int i = 0; i < 4; i++) {
      gload_lds16(aP + i * 16384, &sm.st.A[(i * 256 + t) * 8]);
      gload_lds16(bP + i * 16384, &sm.st.B[(i * 256 + t) * 8]);
    }
    aP += BK; bP += BK;
    __syncthreads();                // drains vmcnt before LDS reads

    s16x8 aF[4], bF[4];
#pragma unroll
    for (int m = 0; m < 4; m++) aF[m] = *(const s16x8*)&sm.st.A[aB0 + m * 1024];
#pragma unroll
    for (int n = 0; n < 4; n++) bF[n] = *(const s16x8*)&sm.st.B[bB0 + n * 1024];
#pragma unroll
    for (int m = 0; m < 4; m++)
#pragma unroll
      for (int n = 0; n < 4; n++)
        acc[m][n] = __builtin_amdgcn_mfma_f32_16x16x32_bf16(aF[m], bF[n], acc[m][n], 0, 0, 0);
#pragma unroll
    for (int m = 0; m < 4; m++) aF[m] = *(const s16x8*)&sm.st.A[(aB0 ^ 32) + m * 1024];
#pragma unroll
    for (int n = 0; n < 4; n++) bF[n] = *(const s16x8*)&sm.st.B[(bB0 ^ 32) + n * 1024];
#pragma unroll
    for (int m = 0; m < 4; m++)
#pragma unroll
      for (int n = 0; n < 4; n++)
        acc[m][n] = __builtin_amdgcn_mfma_f32_16x16x32_bf16(aF[m], bF[n], acc[m][n], 0, 0, 0);
    __syncthreads();
  }

  // ======== epilogue: scan -> LDS merge (two row-half passes) ========
  // C/D layout: acc[m][n][r] -> row wr*64+m*16+hi*4+r, col wc*64+n*16+rr
  int wcbase = wc * 64;

  auto scan_write = [&]() {
#pragma unroll
    for (int m = 0; m < 4; m++)
#pragma unroll
      for (int r = 0; r < 4; r++) {
        float v0 = acc[m][0][r], v1 = acc[m][1][r], v2 = acc[m][2][r], v3 = acc[m][3][r];
        // top2-of-4 (col order 0<1<2<3; ties keep lower col)
        float a1, a2, d1, d2, t1, t2; int i1, i2, j1, j2, u1, u2;
        if (v1 > v0) { a1 = v1; i1 = 1; a2 = v0; i2 = 0; } else { a1 = v0; i1 = 0; a2 = v1; i2 = 1; }
        if (v3 > v2) { d1 = v3; j1 = 3; d2 = v2; j2 = 2; } else { d1 = v2; j1 = 2; d2 = v3; j2 = 3; }
        if (a1 >= d1) { t1 = a1; u1 = i1; if (d1 > a2) { t2 = d1; u2 = j1; } else { t2 = a2; u2 = i2; } }
        else          { t1 = d1; u1 = j1; if (a1 >= d2) { t2 = a1; u2 = i1; } else { t2 = d2; u2 = j2; } }
        int col1 = wcbase + u1 * 16 + rr, col2 = wcbase + u2 * 16 + rr;
        u64 k1 = ((u64)ordf(t1) << 32) | (unsigned)(~col1);
        u64 k2 = ((u64)ordf(t2) << 32) | (unsigned)(~col2);
        int rloc = m * 16 + hi * 4 + r;          // 0..63 within this wr half
        int e = wc * 16 + rr;                    // 0..31
        int slot = (e + rloc) & 31;
        sm.ep[rloc * 33 + slot] =
            make_uint4((unsigned)k1, (unsigned)(k1 >> 32), (unsigned)k2, (unsigned)(k2 >> 32));
      }
  };

  auto finalize_store = [&](int pass) {
    u64 K1 = 0, K2 = 0;
#pragma unroll 4
    for (int e = 0; e < 32; e++) {
      uint4 qq = sm.ep[t * 33 + ((e + t) & 31)];
      u64 e1 = ((u64)qq.y << 32) | qq.x;
      u64 e2 = ((u64)qq.w << 32) | qq.z;
      if (e1 > K1) { K2 = (K1 > e2) ? K1 : e2; K1 = e1; }
      else if (e1 > K2) { K2 = e1; }
    }
    int rowl = pass * 64 + t;
    size_t rowg = (size_t)by * BM + rowl;
    float f1 = unordf((unsigned)(K1 >> 32));
    float f2 = unordf((unsigned)(K2 >> 32));
    int c1 = (int)(~(unsigned)K1);
    int c2 = (int)(~(unsigned)K2);
    pv[(size_t)(bx * 2 + 0) * N_ROWS + rowg] = f1;
    pv[(size_t)(bx * 2 + 1) * N_ROWS + rowg] = f2;
    pi[(size_t)(bx * 2 + 0) * N_ROWS + rowg] = bx * BN + c1;
    pi[(size_t)(bx * 2 + 1) * N_ROWS + rowg] = bx * BN + c2;
  };

  if (wr == 0) scan_write();
  __syncthreads();
  if (t < 64) finalize_store(0);
  __syncthreads();
  if (wr == 1) scan_write();
  __syncthreads();
  if (t < 64) finalize_store(1);
}

// ---- collapse: per-row max over 128 entries + candidate list (argmax first) ----
__global__ void collapse(const float* __restrict__ pv, const int* __restrict__ pi,
                         int* __restrict__ cand) {
  int r = blockIdx.x * 256 + threadIdx.x;
  float mx = -1e30f; int be = 0;
#pragma unroll 8
  for (int e = 0; e < 2 * NB; e++) {
    float v = pv[(size_t)e * N_ROWS + r];
    if (v > mx) { mx = v; be = e; }
  }
  float thr = mx - MARGIN;
  cand[r * 8 + 1] = pi[(size_t)be * N_ROWS + r];
  int cnt = 1;
  for (int e = 0; e < 2 * NB; e++) {
    if (e == be) continue;
    float v = pv[(size_t)e * N_ROWS + r];
    if (v >= thr && cnt < 7) { cand[r * 8 + 1 + cnt] = pi[(size_t)e * N_ROWS + r]; cnt++; }
  }
  cand[r * 8] = cnt;
}

// ---- wave-per-row: rescore candidates fp32, emit quantized_st + partial loss ----
__global__ void reduce_rescore(
    const float* __restrict__ X, const float* __restrict__ W,
    const float* __restrict__ xnorm, const float* __restrict__ wnorm,
    const float* __restrict__ wn2, const int* __restrict__ cand,
    float* __restrict__ out, float* __restrict__ partial, float* __restrict__ outIdx) {
  int row = blockIdx.x * 4 + (threadIdx.x >> 6);
  int l = threadIdx.x & 63;

  float xnrm = xnorm[row];
  const float4* xp = (const float4*)&X[(size_t)row * DIM + l * 8];
  float4 a0 = xp[0], a1 = xp[1];
  float xq[8];
  xq[0] = a0.x / xnrm; xq[1] = a0.y / xnrm; xq[2] = a0.z / xnrm; xq[3] = a0.w / xnrm;
  xq[4] = a1.x / xnrm; xq[5] = a1.y / xnrm; xq[6] = a1.z / xnrm; xq[7] = a1.w / xnrm;

  int cnt = cand[row * 8];
  float bestDist = 1e30f; int bestIdx = 0x7fffffff;
  for (int ci = 0; ci < cnt; ci++) {
    int c = cand[row * 8 + 1 + ci];
    float wnr = wnorm[c];
    const float4* wp = (const float4*)&W[(size_t)c * DIM + l * 8];
    float4 w0 = wp[0], w1 = wp[1];
    float d = xq[0] * (w0.x / wnr) + xq[1] * (w0.y / wnr)
            + xq[2] * (w0.z / wnr) + xq[3] * (w0.w / wnr)
            + xq[4] * (w1.x / wnr) + xq[5] * (w1.y / wnr)
            + xq[6] * (w1.z / wnr) + xq[7] * (w1.w / wnr);
#pragma unroll
    for (int o = 32; o; o >>= 1) d += __shfl_xor(d, o);
    float dist = wn2[c] - 2.0f * d;
    if (dist < bestDist || (dist == bestDist && c < bestIdx)) { bestDist = dist; bestIdx = c; }
  }

  int c = bestIdx;
  float wnr = wnorm[c];
  const float4* wp = (const float4*)&W[(size_t)c * DIM + l * 8];
  float4 w0 = wp[0], w1 = wp[1];
  float q[8];
  q[0] = w0.x / wnr; q[1] = w0.y / wnr; q[2] = w0.z / wnr; q[3] = w0.w / wnr;
  q[4] = w1.x / wnr; q[5] = w1.y / wnr; q[6] = w1.z / wnr; q[7] = w1.w / wnr;
  float4 o0, o1;
  o0.x = xq[0] + (q[0] - xq[0]); o0.y = xq[1] + (q[1] - xq[1]);
  o0.z = xq[2] + (q[2] - xq[2]); o0.w = xq[3] + (q[3] - xq[3]);
  o1.x = xq[4] + (q[4] - xq[4]); o1.y = xq[5] + (q[5] - xq[5]);
  o1.z = xq[6] + (q[6] - xq[6]); o1.w = xq[7] + (q[7] - xq[7]);
  float4* op = (float4*)&out[(size_t)row * DIM + l * 8];
  op[0] = o0; op[1] = o1;
  float ssum = 0.f;
#pragma unroll
  for (int j = 0; j < 8; j++) { float df = q[j] - xq[j]; ssum += df * df; }
#pragma unroll
  for (int o = 32; o; o >>= 1) ssum += __shfl_xor(ssum, o);
  if (l == 0) { partial[row] = ssum; outIdx[row] = (float)c; }
}

// ---- loss reduction: 128 blocks, one elem/thread, wave-reduce + atomic ----
__global__ void reduce_loss(const float* __restrict__ partial, float* __restrict__ accum) {
  int i = blockIdx.x * 256 + threadIdx.x;
  float s = partial[i];
#pragma unroll
  for (int o = 32; o; o >>= 1) s += __shfl_xor(s, o);
  if ((threadIdx.x & 63) == 0) atomicAdd(accum, s);
}

__global__ void write_loss(const float* __restrict__ accum, float* __restrict__ out) {
  out[0] = (float)(1.25 * (double)accum[0] / (double)((size_t)N_ROWS * DIM));
}

extern "C" void kernel_launch(void* const* d_in, const int* in_sizes, int n_in,
                              void* d_out, int out_size, void* d_ws, size_t ws_size,
                              hipStream_t stream) {
  const float* x = (const float*)d_in[0];
  const float* W = (const float*)d_in[1];
  float* out = (float*)d_out;
  char* ws = (char*)d_ws;

  unsigned short* wn16 = (unsigned short*)(ws);                 //  8 MB
  unsigned short* xn16 = (unsigned short*)(ws + 8388608);       // 32 MB (dead after gemm)
  float* wnorm = (float*)(ws + 41943040);                       // 32 KB
  float* wn2   = (float*)(ws + 41975808);                       // 32 KB
  float* xnorm = (float*)(ws + 42008576);                       // 128 KB
  float* pv    = (float*)(ws + 42139648);                       // 16 MB
  int*   pi    = (int*)  (ws + 58916864);                       // 16 MB
  float* accum = (float*)(ws + 75694080);                       // 4 B
  // these reuse the dead xn16 region (only written after gemm_top2):
  float* partial = (float*)(ws + 8388608);                      // 128 KB
  int*   cand    = (int*)  (ws + 8519680);                      // 1 MB

  hipMemsetAsync(accum, 0, sizeof(float), stream);
  prep_all<<<K_CODES / 4 + N_ROWS / 4, 256, 0, stream>>>(W, x, wn16, xn16, wnorm, wn2, xnorm);
  dim3 grid(NB, N_ROWS / BM);
  gemm_top2<<<grid, 256, 0, stream>>>(xn16, wn16, pv, pi);
  collapse<<<N_ROWS / 256, 256, 0, stream>>>(pv, pi, cand);
  reduce_rescore<<<N_ROWS / 4, 256, 0, stream>>>(
      x, W, xnorm, wnorm, wn2, cand, out, partial,
      out + (size_t)N_ROWS * DIM + 1);
  reduce_loss<<<N_ROWS / 256, 256, 0, stream>>>(partial, accum);
  write_loss<<<1, 1, 0, stream>>>(accum, out + (size_t)N_ROWS * DIM);
}